// Round 6
// baseline (469.046 us; speedup 1.0000x reference)
//
#include <hip/hip_runtime.h>
#include <cstdint>
#include <cstddef>

#define NN 50000
#define EE 1600000
#define KB ((NN + 127) / 128)            // 391 buckets of 128 nodes
#define PCHUNK 4096                      // edges per passA block
#define SLICE 8064                       // slots per bucket slice (mean 4092, +62 sigma)
#define GPAD 32                          // gbcnt padding: 1 counter per 128B line

typedef __attribute__((ext_vector_type(8))) short short8;
typedef __attribute__((ext_vector_type(8))) unsigned short ushort8;
typedef __attribute__((ext_vector_type(4))) float float4v;
typedef __attribute__((ext_vector_type(2))) float floatx2;

__device__ __forceinline__ float bf2f(unsigned short u) {
    union { unsigned int i; float f; } v; v.i = ((unsigned int)u) << 16; return v.f;
}
__device__ __forceinline__ unsigned short f2bf(float f) {
    union { float f; unsigned int i; } v; v.f = f;
    unsigned int r = v.i + 0x7FFF + ((v.i >> 16) & 1);   // RNE
    return (unsigned short)(r >> 16);
}

// ---------------- fp32 -> bf16 convert ----------------
__global__ __launch_bounds__(256) void cvt_kernel(const float* __restrict__ in,
                                                  unsigned short* __restrict__ out, int n) {
    int i = (blockIdx.x * 256 + threadIdx.x) * 4;
    if (i + 3 >= n) {
        for (int k = i; k < n; k++) out[k] = f2bf(in[k]);
        return;
    }
    float4 v = *(const float4*)(in + i);
    ushort4 o;
    o.x = f2bf(v.x); o.y = f2bf(v.y); o.z = f2bf(v.z); o.w = f2bf(v.w);
    *(ushort4*)(out + i) = o;
}

// fused convert of the 3 weight matrices (one launch)
__global__ __launch_bounds__(256) void cvt_w_kernel(
    const float* __restrict__ w1, unsigned short* __restrict__ o1,   // 32768
    const float* __restrict__ w2, unsigned short* __restrict__ o2,   // 65536
    const float* __restrict__ w3, unsigned short* __restrict__ o3)   // 65536
{
    int i = (blockIdx.x * 256 + threadIdx.x) * 4;
    const float* in; unsigned short* out;
    if (i < 32768) { in = w1; out = o1; }
    else if (i < 32768 + 65536) { in = w2; out = o2; i -= 32768; }
    else { in = w3; out = o3; i -= 32768 + 65536; }
    float4 v = *(const float4*)(in + i);
    ushort4 o;
    o.x = f2bf(v.x); o.y = f2bf(v.y); o.z = f2bf(v.z); o.w = f2bf(v.w);
    *(ushort4*)(out + i) = o;
}

// ---------------- binning pass A: bucket-major partition (NO per-node hist) ----
__global__ __launch_bounds__(256) void passA_kernel(
    const int* __restrict__ src, const int* __restrict__ dst,
    const float* __restrict__ ea, int* __restrict__ gbcnt,
    uint2* __restrict__ tmp, int E)
{
    __shared__ int bh[KB];
    __shared__ int bbase[KB];
    const int t = threadIdx.x;
    const int base_e = blockIdx.x * PCHUNK;
    for (int i = t; i < KB; i += 256) bh[i] = 0;
    __syncthreads();

    unsigned int rlo[16]; int dd[16];
    #pragma unroll
    for (int u = 0; u < 16; u++) {
        int e = base_e + u * 256 + t;
        dd[u] = -1;
        if (e < E) {
            int d = dst[e], s = src[e];
            if ((unsigned)d < NN && (unsigned)s < NN) {
                const float4* p = (const float4*)(ea + (size_t)e * 8);
                float4 a = p[0], b = p[1];
                float w = (a.x + a.y + a.z + a.w + b.x + b.y + b.z + b.w) * 0.125f;
                rlo[u] = (unsigned)s | ((unsigned)f2bf(w) << 16);
                dd[u] = d;
                atomicAdd(&bh[d >> 7], 1);
            }
        }
    }
    __syncthreads();
    for (int i = t; i < KB; i += 256) {
        int c = bh[i];
        bbase[i] = (c > 0) ? atomicAdd(&gbcnt[i * GPAD], c) : 0;
        bh[i] = 0;                       // reuse as per-bucket cursor
    }
    __syncthreads();
    #pragma unroll
    for (int u = 0; u < 16; u++) {
        if (dd[u] >= 0) {
            int b = dd[u] >> 7;
            int pos = bbase[b] + atomicAdd(&bh[b], 1);
            if (pos < SLICE)
                tmp[(size_t)b * SLICE + pos] = (uint2){rlo[u], (unsigned)(dd[u] & 127)};
        }
    }
}

// ---------------- binning pass B: per-bucket hist + prefix + counting sort ----
__global__ __launch_bounds__(256) void passB_kernel(
    const uint2* __restrict__ tmp, const int* __restrict__ gbcnt,
    int* __restrict__ rowptr, unsigned int* __restrict__ recs)
{
    __shared__ int cnts[KB];
    __shared__ int lh[128];   // node hist -> cursor
    __shared__ int lp[128];   // inclusive prefix
    __shared__ int sboff;
    const int b = blockIdx.x;
    const int t = threadIdx.x;
    for (int i = t; i < KB; i += 256) cnts[i] = gbcnt[i * GPAD];
    if (t < 128) lh[t] = 0;
    __syncthreads();
    if (t == 0) {
        int s = 0;
        for (int i = 0; i < b; i++) s += cnts[i];
        sboff = s;
        if (b == KB - 1) rowptr[NN] = s + cnts[b];
    }
    __syncthreads();
    int cnt = cnts[b]; if (cnt > SLICE) cnt = SLICE;
    const uint2* slice = tmp + (size_t)b * SLICE;
    for (int i = t; i < cnt; i += 256) atomicAdd(&lh[slice[i].y], 1);
    __syncthreads();
    if (t < 128) lp[t] = lh[t];
    __syncthreads();
    #pragma unroll
    for (int off = 1; off < 128; off <<= 1) {
        int v = 0;
        if (t < 128 && t >= off) v = lp[t - off];
        __syncthreads();
        if (t < 128) lp[t] += v;
        __syncthreads();
    }
    const int node0 = b * 128;
    const int nnodes = (NN - node0 < 128) ? (NN - node0) : 128;
    if (t < nnodes) {
        int excl = lp[t] - lh[t] + sboff;   // exclusive prefix + bucket base
        rowptr[node0 + t] = excl;
        lh[t] = excl;                       // reuse as global cursor
    }
    __syncthreads();
    for (int i = t; i < cnt; i += 256) {
        uint2 r = slice[i];
        int pos = atomicAdd(&lh[r.y], 1);
        recs[pos] = r.x;
    }
}

// ---------------- gather-aggregate, bf16 input (layer 1, C=128) ----------------
// One wave per node; quarter-wave (16 ln x 16B) per edge row.
// Masked 32-edge batches: 8 recs + 8 row loads in flight -> one dependent
// round covers a mean-degree node (latency-bound fix). Clamped lanes re-read
// recs[end-1] (L1-hit) with w=0 -> exact no-op, per-lane order unchanged.
template <bool HASW>
__global__ __launch_bounds__(256) void gather_bf(
    const unsigned short* __restrict__ h, const int* __restrict__ rowptr,
    const unsigned int* __restrict__ recs, unsigned short* __restrict__ agg)
{
    int node = blockIdx.x * 4 + (threadIdx.x >> 6);
    int lane = threadIdx.x & 63;
    if (node >= NN) return;
    int beg = rowptr[node], end = rowptr[node + 1];

    const int quar = lane >> 4;
    const int l16  = lane & 15;

    float a[8] = {0.f, 0.f, 0.f, 0.f, 0.f, 0.f, 0.f, 0.f};

    for (int j = beg; j < end; j += 32) {
        unsigned int r[8]; ushort8 v[8];
        #pragma unroll
        for (int u = 0; u < 8; u++) {
            int idx = j + 4 * u + quar;
            r[u] = recs[idx < end ? idx : end - 1];
        }
        #pragma unroll
        for (int u = 0; u < 8; u++)
            v[u] = *(const ushort8*)(h + (size_t)(r[u] & 0xFFFF) * 128 + l16 * 8);
        #pragma unroll
        for (int u = 0; u < 8; u++) {
            int idx = j + 4 * u + quar;
            float w = (idx < end) ? (HASW ? bf2f((unsigned short)(r[u] >> 16)) : 1.f) : 0.f;
            #pragma unroll
            for (int k = 0; k < 8; k++) a[k] += w * bf2f(v[u][k]);
        }
    }
    #pragma unroll
    for (int k = 0; k < 8; k++) {
        a[k] += __shfl_xor(a[k], 16, 64);
        a[k] += __shfl_xor(a[k], 32, 64);
    }
    if (quar == 0) {
        ushort8 o;
        #pragma unroll
        for (int k = 0; k < 8; k++) o[k] = f2bf(a[k]);
        *(ushort8*)(agg + (size_t)node * 128 + l16 * 8) = o;
    }
}

// ---------------- gather-aggregate, fp8 input (layers 2/3, C=256) ----------------
// Row = 256 B fp8; quarter-wave (16 ln x 16B) = one full row; masked 32-edge
// batches with 8 rows in flight (same MLP rationale as gather_bf).
template <bool HASW>
__global__ __launch_bounds__(256) void gather_fp8(
    const unsigned char* __restrict__ h, const int* __restrict__ rowptr,
    const unsigned int* __restrict__ recs, unsigned short* __restrict__ agg)
{
    int node = blockIdx.x * 4 + (threadIdx.x >> 6);
    int lane = threadIdx.x & 63;
    if (node >= NN) return;
    int beg = rowptr[node], end = rowptr[node + 1];

    const int slot = lane >> 4;
    const int l16  = lane & 15;

    float a[16];
    #pragma unroll
    for (int k = 0; k < 16; k++) a[k] = 0.f;

    for (int j = beg; j < end; j += 32) {
        unsigned int r[8]; uint4 v[8];
        #pragma unroll
        for (int u = 0; u < 8; u++) {
            int idx = j + 4 * u + slot;
            r[u] = recs[idx < end ? idx : end - 1];
        }
        #pragma unroll
        for (int u = 0; u < 8; u++)
            v[u] = *(const uint4*)(h + (size_t)(r[u] & 0xFFFF) * 256 + l16 * 16);
        #pragma unroll
        for (int u = 0; u < 8; u++) {
            int idx = j + 4 * u + slot;
            float w = (idx < end) ? (HASW ? bf2f((unsigned short)(r[u] >> 16)) : 1.f) : 0.f;
            unsigned int ww[4] = {v[u].x, v[u].y, v[u].z, v[u].w};
            #pragma unroll
            for (int wi = 0; wi < 4; wi++) {
                floatx2 lo = __builtin_amdgcn_cvt_pk_f32_fp8(ww[wi], false);
                floatx2 hi = __builtin_amdgcn_cvt_pk_f32_fp8(ww[wi], true);
                a[4 * wi + 0] += w * lo.x;
                a[4 * wi + 1] += w * lo.y;
                a[4 * wi + 2] += w * hi.x;
                a[4 * wi + 3] += w * hi.y;
            }
        }
    }
    #pragma unroll
    for (int k = 0; k < 16; k++) {
        a[k] += __shfl_xor(a[k], 16, 64);
        a[k] += __shfl_xor(a[k], 32, 64);
    }
    if (slot == 0) {
        ushort8 o0, o1;
        #pragma unroll
        for (int k = 0; k < 8; k++) { o0[k] = f2bf(a[k]); o1[k] = f2bf(a[k + 8]); }
        *(ushort8*)(agg + (size_t)node * 256 + l16 * 16) = o0;
        *(ushort8*)(agg + (size_t)node * 256 + l16 * 16 + 8) = o1;
    }
}

// ---------------- MFMA GEMM: out[M,256] = A[M,CIN](bf16) @ W[256,CIN](bf16)^T ----
// MODE 0: +bias, fp32 out. MODE 1: +bias, BN, ReLU, fp8(e4m3) out.
template <int CIN, int MODE>
__global__ __launch_bounds__(256) void mm_mfma(
    const unsigned short* __restrict__ A, const unsigned short* __restrict__ W,
    const float* __restrict__ bias,
    const float* __restrict__ gamma, const float* __restrict__ beta,
    const float* __restrict__ mean, const float* __restrict__ var,
    void* __restrict__ out, int M)
{
    const int lane = threadIdx.x & 63;
    const int wave = threadIdx.x >> 6;
    const int quad = lane >> 4;
    const int l16  = lane & 15;
    const int row0 = blockIdx.x * 128 + (wave & 1) * 64;
    const int col0 = blockIdx.y * 128 + (wave >> 1) * 64;

    float4v acc[4][4] = {};

    for (int k0 = 0; k0 < CIN; k0 += 32) {
        const int ka = k0 + quad * 8;
        short8 af[4], bf[4];
        #pragma unroll
        for (int i = 0; i < 4; i++) {
            int r = row0 + i * 16 + l16;
            af[i] = (r < M) ? *(const short8*)(A + (size_t)r * CIN + ka) : (short8)0;
            bf[i] = *(const short8*)(W + (size_t)(col0 + i * 16 + l16) * CIN + ka);
        }
        #pragma unroll
        for (int mi = 0; mi < 4; mi++)
            #pragma unroll
            for (int ni = 0; ni < 4; ni++)
                acc[mi][ni] = __builtin_amdgcn_mfma_f32_16x16x32_bf16(
                    af[mi], bf[ni], acc[mi][ni], 0, 0, 0);
    }

    float cb[4], cmu[4], cinv[4], cbe[4];
    #pragma unroll
    for (int ni = 0; ni < 4; ni++) {
        int gc = col0 + ni * 16 + l16;
        cb[ni] = bias[gc];
        if (MODE == 1) {
            cmu[ni]  = mean[gc];
            cinv[ni] = gamma[gc] * rsqrtf(var[gc] + 1e-5f);
            cbe[ni]  = beta[gc];
        }
    }
    #pragma unroll
    for (int mi = 0; mi < 4; mi++) {
        #pragma unroll
        for (int reg = 0; reg < 4; reg++) {
            int gr = row0 + mi * 16 + quad * 4 + reg;
            if (gr >= M) continue;
            #pragma unroll
            for (int ni = 0; ni < 4; ni++) {
                int gc = col0 + ni * 16 + l16;
                float v = acc[mi][ni][reg] + cb[ni];
                if (MODE == 1) {
                    v = (v - cmu[ni]) * cinv[ni] + cbe[ni];
                    v = fmaxf(v, 0.f);
                    int pk = __builtin_amdgcn_cvt_pk_fp8_f32(v, v, 0, false);
                    ((unsigned char*)out)[(size_t)gr * 256 + gc] = (unsigned char)(pk & 0xFF);
                } else {
                    ((float*)out)[(size_t)gr * 256 + gc] = v;
                }
            }
        }
    }
}

extern "C" void kernel_launch(void* const* d_in, const int* in_sizes, int n_in,
                              void* d_out, int out_size, void* d_ws, size_t ws_size,
                              hipStream_t stream) {
    const float* x   = (const float*)d_in[0];
    const int*   ei  = (const int*)d_in[1];   // [2, E] int32
    const float* ea  = (const float*)d_in[2];
    const float* W1  = (const float*)d_in[3];
    const float* b1  = (const float*)d_in[4];
    const float* g1  = (const float*)d_in[5];
    const float* be1 = (const float*)d_in[6];
    const float* m1  = (const float*)d_in[7];
    const float* v1  = (const float*)d_in[8];
    const float* W2  = (const float*)d_in[9];
    const float* b2  = (const float*)d_in[10];
    const float* g2  = (const float*)d_in[11];
    const float* be2 = (const float*)d_in[12];
    const float* m2  = (const float*)d_in[13];
    const float* v2  = (const float*)d_in[14];
    const float* W3  = (const float*)d_in[15];
    const float* b3  = (const float*)d_in[16];

    const int* src = ei;
    const int* dst = ei + EE;

    // workspace carve-up (256B-aligned segments)
    char* p = (char*)d_ws;
    auto alloc = [&](size_t bytes) { char* r = p; p += (bytes + 255) & ~255ULL; return r; };
    int*            rowptr    = (int*)alloc((NN + 1) * 4);
    int*            gbcnt     = (int*)alloc((size_t)KB * GPAD * 4);   // padded counters
    unsigned int*   recs      = (unsigned int*)alloc((size_t)EE * 4);
    unsigned short* xb        = (unsigned short*)alloc((size_t)NN * 128 * 2);
    unsigned short* W1b       = (unsigned short*)alloc(256 * 128 * 2);
    unsigned short* W2b       = (unsigned short*)alloc(256 * 256 * 2);
    unsigned short* W3b       = (unsigned short*)alloc(256 * 256 * 2);
    unsigned short* agg       = (unsigned short*)alloc((size_t)NN * 256 * 2);
    unsigned char*  hbuf      = (unsigned char*)alloc((size_t)NN * 256);   // fp8 e4m3
    float*          out       = (float*)d_out;

    // tmp (bucket slices, 391*8064*8B = 25.22 MB) aliases agg (25.6 MB):
    // tmp is dead after passB; agg's first write is gather_bf (later).
    uint2* tmp = (uint2*)agg;

    const int gblocks = (NN + 3) / 4;
    const int mtiles  = (NN + 127) / 128;
    const int pblocks = (EE + PCHUNK - 1) / PCHUNK;   // 391

    // converts
    cvt_kernel<<<(NN * 128 / 4 + 255) / 256, 256, 0, stream>>>(x, xb, NN * 128);
    cvt_w_kernel<<<(32768 + 65536 + 65536) / 4 / 256, 256, 0, stream>>>(
        W1, W1b, W2, W2b, W3, W3b);

    // CSR build: partition -> per-bucket hist+prefix+sort (no global per-node atomics)
    hipMemsetAsync(gbcnt, 0, (size_t)KB * GPAD * 4, stream);
    passA_kernel<<<pblocks, 256, 0, stream>>>(src, dst, ea, gbcnt, tmp, EE);
    passB_kernel<<<KB, 256, 0, stream>>>(tmp, gbcnt, rowptr, recs);

    // ---- layer 1: gather x (bf16, C=128) -> MFMA W1 + BN1 + ReLU -> h (fp8) ----
    gather_bf<true><<<gblocks, 256, 0, stream>>>(xb, rowptr, recs, agg);
    mm_mfma<128, 1><<<dim3(mtiles, 2), 256, 0, stream>>>(
        agg, W1b, b1, g1, be1, m1, v1, hbuf, NN);

    // ---- layer 2: gather h (fp8, C=256) -> MFMA W2 + BN2 + ReLU -> h (fp8) ----
    gather_fp8<true><<<gblocks, 256, 0, stream>>>(hbuf, rowptr, recs, agg);
    mm_mfma<256, 1><<<dim3(mtiles, 2), 256, 0, stream>>>(
        agg, W2b, b2, g2, be2, m2, v2, hbuf, NN);

    // ---- layer 3: gather h (fp8, C=256, no weight) -> MFMA W3 + bias -> out (fp32) ----
    gather_fp8<false><<<gblocks, 256, 0, stream>>>(hbuf, rowptr, recs, agg);
    mm_mfma<256, 0><<<dim3(mtiles, 2), 256, 0, stream>>>(
        agg, W3b, b3, nullptr, nullptr, nullptr, nullptr, out, NN);
}